// Round 22
// baseline (80.379 us; speedup 1.0000x reference)
//
#include <hip/hip_runtime.h>
#include <cstdint>

#define BB 16
#define NN 25200
#define NCLS 80
#define NF (5 + NCLS)
#define MAXDET 300
#define MTGT 50
#define CONF 0.8f
#define NMSTH 0.4f
#define WORDS 10
#define NBINS 2048
#define CAPALL 8192
#define SBUF 2048
#define APB 64
#define CPB 394                             // chunks per batch: 393x64 + 48 (no straddle)
#define SLOTK 48                            // per-chunk slot (Binom(64,.19)>=48 ~ 1e-30)
#define SCORE_BLOCKS (BB * CPB)             // 6304
#define NTGT_BLOCKS ((BB * MTGT + 127) / 128)
#define HSTRIDE 33

// workspace byte offsets
#define WS_CNTS 0                                        // 6304 ints
#define WS_KEYS 32768                                    // 6304*48*8
#define WS_GBOX (WS_KEYS + (size_t)SCORE_BLOCKS * SLOTK * 8)
#define WS_GLAB (WS_GBOX + (size_t)SCORE_BLOCKS * SLOTK * 16)
#define WS_DBOX (WS_GLAB + (size_t)SCORE_BLOCKS * SLOTK * 4)
#define WS_DLAB (WS_DBOX + (size_t)BB * MAXDET * 16)
#define WS_DSC  (WS_DLAB + (size_t)BB * MAXDET * 4)
#define WS_SUPP (WS_DSC + (size_t)BB * MAXDET * 4)

// output float offsets (return order: pb, ps, pl, pv, tb, ts, tl, tv)
#define O_PB 0
#define O_PS (BB * MAXDET * 4)
#define O_PL (O_PS + BB * MAXDET)
#define O_PV (O_PL + BB * MAXDET)
#define O_TB (O_PV + BB * MAXDET)
#define O_TS (O_TB + BB * MTGT * 4)
#define O_TL (O_TS + BB * MTGT)
#define O_TV (O_TL + BB * MTGT)

// Proven scorer + per-chunk compact emitting (key, box, label). ~22-24 us,
// HBM roofline. Tail blocks: target transform. (R20/R21, verbatim)
__global__ __launch_bounds__(128) void k_score(const float* __restrict__ preds,
                                               int* __restrict__ cnts,
                                               unsigned long long* __restrict__ keys,
                                               float* __restrict__ gbox,
                                               int* __restrict__ glabel,
                                               const float* __restrict__ tt,
                                               const int* __restrict__ len,
                                               float* __restrict__ out) {
    __shared__ float st[APB * NF];          // 21760 B
    __shared__ int wbase0;
    int tid = threadIdx.x;
    int bid = blockIdx.x;

    if (bid >= SCORE_BLOCKS) {              // fused target transform
        int t = (bid - SCORE_BLOCKS) * 128 + tid;
        if (t < BB * MTGT) {
            int b = t / MTGT, m = t - b * MTGT;
            const float* row = tt + (size_t)t * 6;
            bool valid = m < len[b];
            float cx = row[0], cy = row[1], w = row[2], h = row[3];
            float x1 = cx - 0.5f * w, y1 = cy - 0.5f * h;
            float* tb = out + O_TB + (size_t)t * 4;
            tb[0] = valid ? x1 : 0.f;
            tb[1] = valid ? y1 : 0.f;
            tb[2] = valid ? (x1 + w) : 0.f;
            tb[3] = valid ? (y1 + h) : 0.f;
            out[O_TS + t] = valid ? row[4] : 0.f;
            out[O_TL + t] = valid ? (float)(int)row[5] : -1.f;
            out[O_TV + t] = valid ? 1.f : 0.f;
        }
        return;
    }

    int b  = bid / CPB;                     // batch
    int cb = bid - b * CPB;                 // chunk within batch
    int count = (cb == CPB - 1) ? (NN - (CPB - 1) * APB) : APB;   // 48 or 64
    int nv4 = count * NF / 4;               // 1020 or 1360 (both exact)

    int w = tid >> 6;                       // wave id (uniform per wave)
    int lane = tid & 63;
    const float4* src = (const float4*)(preds + ((size_t)b * NN + (size_t)cb * APB) * NF);
    #pragma unroll
    for (int i = 0; i < 11; ++i) {
        int idx = i * 128 + tid;
        if (idx < nv4) {
            __builtin_amdgcn_global_load_lds(
                (const __attribute__((address_space(1))) void*)(src + idx),
                (__attribute__((address_space(3))) void*)(st + (i * 128 + w * 64) * 4),
                16, 0, 0);
        }
    }
    __syncthreads();                        // drains vmcnt -> LDS valid

    int a = tid >> 1, h = tid & 1;          // anchor, half
    const float* row = st + a * NF;
    const float* cls = row + 5 + h * 40;
    float v0 = cls[0], v1 = cls[1], v2 = cls[2], v3 = cls[3];
    int   i0 = 0,      i1 = 1,      i2 = 2,      i3 = 3;
    #pragma unroll
    for (int f = 4; f < 40; f += 4) {       // 4 independent (val,idx) chains
        if (cls[f]     > v0) { v0 = cls[f];     i0 = f; }
        if (cls[f + 1] > v1) { v1 = cls[f + 1]; i1 = f + 1; }
        if (cls[f + 2] > v2) { v2 = cls[f + 2]; i2 = f + 2; }
        if (cls[f + 3] > v3) { v3 = cls[f + 3]; i3 = f + 3; }
    }
    float v = v0; int ia = i0;              // merge with index tie-break
    if (v1 > v || (v1 == v && i1 < ia)) { v = v1; ia = i1; }
    if (v2 > v || (v2 == v && i2 < ia)) { v = v2; ia = i2; }
    if (v3 > v || (v3 == v && i3 < ia)) { v = v3; ia = i3; }
    int ci = h * 40 + ia;
    float ov = __shfl_xor(v, 1);
    int   oi = __shfl_xor(ci, 1);
    if (ov > v || (ov == v && oi < ci)) { v = ov; ci = oi; }  // lower class on tie
    float s = row[4] * v;                   // single f32 mul, bit-exact vs np

    bool pass = (h == 0) && (a < count) && (s > CONF);
    unsigned long long mask = __ballot(pass);
    int wcnt = __popcll(mask);
    if (w == 0 && lane == 0) wbase0 = wcnt;
    __syncthreads();
    int base = (w == 0) ? 0 : wbase0;
    if (pass) {
        int pos = base + __popcll(mask & ((1ull << lane) - 1ull));
        if (pos < SLOTK) {
            unsigned u = __float_as_uint(s);
            unsigned inv = (unsigned)(NN - 1 - (cb * APB + a));  // 15 bits
            unsigned slot = (unsigned)(cb * SLOTK + pos);        // 15 bits used of 17
            size_t g = (size_t)bid * SLOTK + pos;
            keys[g] = ((unsigned long long)u << 32) |
                      (unsigned long long)((inv << 17) | slot);
            float cx = row[0], cy = row[1], ww = row[2], hh = row[3];
            float x1 = cx - 0.5f * ww, y1 = cy - 0.5f * hh;      // fma-safe
            float4 bx = { x1, y1, x1 + ww, y1 + hh };
            ((float4*)gbox)[g] = bx;
            glabel[g] = ci;
        }
    }
    if (w == 1 && lane == 0) {
        int tot = base + wcnt;
        cnts[bid] = tot < SLOTK ? tot : SLOTK;
    }
}

// Selection A-E (R21 k_post minus F/G): counts scan + key copy + hist, cut,
// filter, rank-by-count, tuple fetch -> per-batch global tables (115 KB,
// L2/L3-resident). Deterministic assembly + exact total order -> bit-identical
// (JAX top_k ties via inv-anchor in key).
__global__ __launch_bounds__(1024) void k_sel(const int* __restrict__ cnts,
                                              const unsigned long long* __restrict__ keys,
                                              const float* __restrict__ gbox,
                                              const int* __restrict__ glabel,
                                              float* __restrict__ dbox,
                                              int* __restrict__ dlab,
                                              float* __restrict__ dsc) {
    __shared__ unsigned long long skall[CAPALL];  // 65536 B
    __shared__ unsigned long long sk[SBUF];
    __shared__ unsigned long long skTop[MAXDET];
    __shared__ int hist[64 * HSTRIDE];
    __shared__ int wsum[16];
    __shared__ int lcnt, lcnt2, scut;
    int b = blockIdx.x;
    int tid = threadIdx.x;
    int lane = tid & 63;
    int wv = tid >> 6;

    if (tid == 0) { lcnt = 0; lcnt2 = 0; }
    for (int i = tid; i < 64 * HSTRIDE; i += 1024) hist[i] = 0;
    if (tid < MAXDET) skTop[tid] = 0ull;
    __syncthreads();

    // phase A: counts -> exclusive block scan -> key copy -> hist
    int c = (tid < CPB) ? cnts[b * CPB + tid] : 0;
    int inc = c;
    #pragma unroll
    for (int d = 1; d < 64; d <<= 1) {
        int o = __shfl_up(inc, d);
        if (lane >= d) inc += o;
    }
    if (lane == 63) wsum[wv] = inc;
    __syncthreads();
    int wbase = 0;
    #pragma unroll
    for (int q = 0; q < 16; ++q) wbase += (q < wv) ? wsum[q] : 0;
    int base = wbase + inc - c;
    if (tid == 1023) lcnt = wbase + inc;
    if (tid < CPB) {
        const unsigned long long* slot = keys + (size_t)(b * CPB + tid) * SLOTK;
        for (int k = 0; k < c; ++k) {
            int p = base + k;
            if (p < CAPALL) skall[p] = slot[k];
        }
    }
    __syncthreads();
    int M = lcnt; if (M > CAPALL) M = CAPALL;
    for (int i = tid; i < M; i += 1024) {
        unsigned u = (unsigned)(skall[i] >> 32);
        int bin = (int)((u - 0x3F400000u) >> 12);   // monotone in (0.8,1.0]
        bin = bin < 0 ? 0 : (bin > NBINS - 1 ? NBINS - 1 : bin);
        atomicAdd(&hist[(bin >> 5) * HSTRIDE + (bin & 31)], 1);
    }
    __syncthreads();

    // phase B: cut bin (largest bin with suffix-count >= 300), one wave
    if (tid < 64) {
        int sb = 0;
        #pragma unroll
        for (int k = 0; k < 32; ++k) sb += hist[lane * HSTRIDE + k];
        int cum = sb;
        #pragma unroll
        for (int d = 1; d < 64; d <<= 1) {
            int o = __shfl_down(cum, d);
            if (lane + d < 64) cum += o;
        }
        unsigned long long m = __ballot(cum >= MAXDET);
        int cutbin = 0;
        if (m) {
            int cutS = 63 - __clzll(m);
            int tail = (cutS < 63) ? __shfl(cum, cutS + 1) : 0;
            int hh = (lane < 32) ? hist[cutS * HSTRIDE + lane] : 0;
            int c2 = hh;
            #pragma unroll
            for (int d = 1; d < 32; d <<= 1) {
                int o = __shfl_down(c2, d);
                if (lane + d < 32) c2 += o;
            }
            c2 += tail;
            unsigned long long m2 = __ballot(lane < 32 && c2 >= MAXDET);
            int cutL = 63 - __clzll(m2);           // m2 != 0 guaranteed
            cutbin = cutS * 32 + cutL;
        }
        if (lane == 0) scut = cutbin;
    }
    __syncthreads();
    int cutbin = scut;

    // phase C: filter skall by bin >= cutbin (wave-aggregated, LDS-only reads)
    for (int i = tid; i < ((M + 1023) & ~1023); i += 1024) {
        bool pass = false;
        unsigned long long key = 0ull;
        if (i < M) {
            key = skall[i];
            unsigned u = (unsigned)(key >> 32);
            int bin = (int)((u - 0x3F400000u) >> 12);
            bin = bin < 0 ? 0 : (bin > NBINS - 1 ? NBINS - 1 : bin);
            pass = bin >= cutbin;
        }
        unsigned long long mask = __ballot(pass);
        int wcnt = __popcll(mask);
        int bs = 0;
        if (lane == 0 && wcnt) bs = atomicAdd(&lcnt2, wcnt);
        bs = __shfl(bs, 0);
        if (pass) {
            int pos = bs + __popcll(mask & ((1ull << lane) - 1ull));
            if (pos < SBUF) sk[pos] = key;
        }
    }
    __syncthreads();

    // phase D: rank-by-counting over M2 ~ 306 survivors (independent loads,
    // unrolled x4 for MLP)
    int M2 = lcnt2; if (M2 > SBUF) M2 = SBUF;
    for (int c2 = tid; c2 < M2; c2 += 1024) {
        unsigned long long key = sk[c2];
        int rank = 0;
        #pragma unroll 4
        for (int j = 0; j < M2; ++j) rank += (sk[j] > key) ? 1 : 0;
        if (rank < MAXDET) skTop[rank] = key;
    }
    __syncthreads();

    // phase E: 300 independent tuple fetches -> global per-batch tables
    if (tid < MAXDET) {
        unsigned long long key = skTop[tid];
        unsigned sbits = (unsigned)(key >> 32);
        int g = b * MAXDET + tid;
        if (sbits) {
            size_t src = (size_t)b * (CPB * SLOTK) + (size_t)(key & 0x1FFFFull);
            ((float4*)dbox)[g] = ((const float4*)gbox)[src];
            dlab[g] = glabel[src];
            dsc[g]  = __uint_as_float(sbits);
        } else {
            float4 zz = { 0.f, 0.f, 0.f, 0.f };
            ((float4*)dbox)[g] = zz;
            dlab[g] = -1;
            dsc[g]  = 0.f;
        }
    }
}

// WIDE suppression mask (R3/R4-proven): 188 blocks, thread per 32-bit word,
// 32 serial IoUs from L2-resident tables, no atomics, each word written once.
// Was the fused post's whale (~4600 LDS instrs on ONE pipe x 16 CUs); here the
// same work spreads over the full machine. IoU op-order = reference; _rn
// blocks fma-contract; exact IEEE div.
__global__ __launch_bounds__(256) void k_mask(const float* __restrict__ dbox,
                                              const int* __restrict__ dlab,
                                              const float* __restrict__ dsc,
                                              unsigned* __restrict__ gsupp) {
    int T = blockIdx.x * 256 + threadIdx.x;
    if (T >= BB * MAXDET * WORDS) return;
    int g  = T / WORDS;                    // b*MAXDET + i
    int jw = T - g * WORDS;
    int b  = g / MAXDET;
    int i  = g - b * MAXDET;

    unsigned word = 0;
    int jbase = jw * 32;
    if (jbase + 31 > i) {                  // word has some j > i
        float4 bi = ((const float4*)dbox)[g];
        int   li = dlab[g];
        float si = dsc[g];
        float ai = __fmul_rn(fmaxf(__fsub_rn(bi.z, bi.x), 0.f),
                             fmaxf(__fsub_rn(bi.w, bi.y), 0.f));
        #pragma unroll 4
        for (int t = 0; t < 32; ++t) {
            int j = jbase + t;
            if (j > i && j < MAXDET) {
                int gj = b * MAXDET + j;
                if (dlab[gj] == li && si > 0.f && dsc[gj] > 0.f) {
                    float4 bj = ((const float4*)dbox)[gj];
                    float xx1 = fmaxf(bi.x, bj.x);
                    float yy1 = fmaxf(bi.y, bj.y);
                    float xx2 = fminf(bi.z, bj.z);
                    float yy2 = fminf(bi.w, bj.w);
                    float iw = fmaxf(__fsub_rn(xx2, xx1), 0.f);
                    float ih = fmaxf(__fsub_rn(yy2, yy1), 0.f);
                    float inter = __fmul_rn(iw, ih);
                    float aj = __fmul_rn(fmaxf(__fsub_rn(bj.z, bj.x), 0.f),
                                         fmaxf(__fsub_rn(bj.w, bj.y), 0.f));
                    float den = __fadd_rn(__fsub_rn(__fadd_rn(ai, aj), inter), 1e-9f);
                    float iou = inter / den;     // exact IEEE div (no fast-math)
                    if (iou > NMSTH) word |= 1u << t;
                }
            }
        }
    }
    gsupp[T] = word;
}

// Finish: 16 blocks x 1024. supp + tables -> LDS COALESCED BY ALL 1024 THREADS
// (R10's fatal flaw was a 64-thread serial load here), then the proven
// single-wave greedy + fused output write with reference masking.
__global__ __launch_bounds__(1024) void k_fin(const float* __restrict__ dbox,
                                              const int* __restrict__ dlab,
                                              const float* __restrict__ dsc,
                                              const unsigned* __restrict__ gsupp,
                                              float* __restrict__ out) {
    __shared__ unsigned ls[MAXDET * WORDS];
    __shared__ float4   sbox[MAXDET];
    __shared__ int      slabel[MAXDET];
    __shared__ float    sscore[MAXDET];
    int b = blockIdx.x;
    int tid = threadIdx.x;
    int lane = tid & 63;

    for (int w = tid; w < MAXDET * WORDS; w += 1024)
        ls[w] = gsupp[b * MAXDET * WORDS + w];
    if (tid < MAXDET) {
        int g = b * MAXDET + tid;
        sbox[tid]   = ((const float4*)dbox)[g];
        slabel[tid] = dlab[g];
        sscore[tid] = dsc[g];
    }
    __syncthreads();

    if (tid < 64) {
        unsigned keep = 0, nzm = 0;
        #pragma unroll
        for (int s = 0; s < 5; ++s) {
            int k = s * 64 + lane;
            bool kb = (k < MAXDET) && (sscore[k] > 0.f);
            unsigned long long m = __ballot(kb);
            if (lane == 2 * s)     keep = (unsigned)m;
            if (lane == 2 * s + 1) keep = (unsigned)(m >> 32);
            unsigned nz = 0;
            if (k < MAXDET) {
                #pragma unroll
                for (int w = 0; w < WORDS; ++w) nz |= ls[k * WORDS + w];
            }
            unsigned long long mn = __ballot(nz != 0u);
            if (lane == 2 * s)     nzm = (unsigned)mn;
            if (lane == 2 * s + 1) nzm = (unsigned)(mn >> 32);
        }

        for (int i = 0; i < MAXDET; ++i) {
            int idx = i >> 5;                       // uniform
            unsigned kw = __shfl(keep, idx);
            unsigned nw = __shfl(nzm, idx);
            if (((kw & nw) >> (i & 31)) & 1u) {
                if (lane < WORDS) keep &= ~ls[i * WORDS + lane];
            }
        }

        #pragma unroll
        for (int s = 0; s < 5; ++s) {
            int k = s * 64 + lane;
            if (k < MAXDET) {
                unsigned kw = __shfl(keep, k >> 5);
                bool kp = (kw >> (k & 31)) & 1u;
                int g = b * MAXDET + k;
                float4 bx = sbox[k];
                float4 zz = { 0.f, 0.f, 0.f, 0.f };
                ((float4*)(out + O_PB))[g] = kp ? bx : zz;
                out[O_PS + g] = kp ? sscore[k] : 0.f;
                out[O_PL + g] = kp ? (float)slabel[k] : -1.f;
                out[O_PV + g] = kp ? 1.f : 0.f;
            }
        }
    }
}

extern "C" void kernel_launch(void* const* d_in, const int* in_sizes, int n_in,
                              void* d_out, int out_size, void* d_ws, size_t ws_size,
                              hipStream_t stream) {
    const float* preds = (const float*)d_in[0];
    const float* tt    = (const float*)d_in[1];
    const int*   len   = (const int*)d_in[2];
    float* out = (float*)d_out;

    char* ws = (char*)d_ws;
    int* cnts = (int*)(ws + WS_CNTS);
    unsigned long long* keys = (unsigned long long*)(ws + WS_KEYS);
    float* gbox  = (float*)(ws + WS_GBOX);
    int*   glabel = (int*)(ws + WS_GLAB);
    float* dbox  = (float*)(ws + WS_DBOX);
    int*   dlab  = (int*)(ws + WS_DLAB);
    float* dsc   = (float*)(ws + WS_DSC);
    unsigned* gsupp = (unsigned*)(ws + WS_SUPP);

    k_score<<<SCORE_BLOCKS + NTGT_BLOCKS, 128, 0, stream>>>(preds, cnts, keys, gbox, glabel, tt, len, out);
    k_sel  <<<BB, 1024, 0, stream>>>(cnts, keys, gbox, glabel, dbox, dlab, dsc);
    k_mask <<<(BB * MAXDET * WORDS + 255) / 256, 256, 0, stream>>>(dbox, dlab, dsc, gsupp);
    k_fin  <<<BB, 1024, 0, stream>>>(dbox, dlab, dsc, gsupp, out);
}